// Round 14
// baseline (16631.013 us; speedup 1.0000x reference)
//
#include <hip/hip_runtime.h>
#include <cstdint>
#include <cstddef>

#define L2E 1.4426950408889634f

typedef __attribute__((ext_vector_type(8))) short short8v;
typedef __attribute__((ext_vector_type(4))) float f32x4;
typedef unsigned long long ull;

__device__ __forceinline__ float fexp2(float x){ return __builtin_amdgcn_exp2f(x); }
__device__ __forceinline__ float frcp(float x){ return __builtin_amdgcn_rcpf(x); }
__device__ __forceinline__ float tanh_f(float x){
  return 1.f - 2.f*frcp(1.f + fexp2(2.f*L2E*x));
}
__device__ __forceinline__ float sigm_f(float x){
  return frcp(1.f + fexp2(-L2E*x));
}
__device__ __forceinline__ float bf2f(ushort u){ return __uint_as_float(((uint32_t)u)<<16); }
__device__ __forceinline__ ushort f2bf(float f){
  uint32_t x = __float_as_uint(f);
  uint32_t r = (x + 0x7FFFu + ((x>>16)&1u)) >> 16;
  return (ushort)r;
}

// ---- coherent (agent-scope) access helpers: only for within-run rewritten data
__device__ __forceinline__ float ld4f(const float* p){
  return __hip_atomic_load((float*)p, __ATOMIC_RELAXED, __HIP_MEMORY_SCOPE_AGENT);
}
__device__ __forceinline__ void st4f(float* p, float v){
  __hip_atomic_store(p, v, __ATOMIC_RELAXED, __HIP_MEMORY_SCOPE_AGENT);
}
__device__ __forceinline__ void st2h(ushort* p, ushort v){
  __hip_atomic_store(p, v, __ATOMIC_RELAXED, __HIP_MEMORY_SCOPE_AGENT);
}
__device__ __forceinline__ short8v ld16h(const ushort* p){
  union { ull u[2]; short8v s; } c;
  c.u[0] = __hip_atomic_load((ull*)p,     __ATOMIC_RELAXED, __HIP_MEMORY_SCOPE_AGENT);
  c.u[1] = __hip_atomic_load((ull*)(p+4), __ATOMIC_RELAXED, __HIP_MEMORY_SCOPE_AGENT);
  return c.s;
}
__device__ __forceinline__ void st8u(ushort* p, ull v){
  __hip_atomic_store((ull*)p, v, __ATOMIC_RELAXED, __HIP_MEMORY_SCOPE_AGENT);
}
// ---- stamped 64b exchange: high 32 = 0xA0000000|step, low 32 = f32 bits.
// One MALL hop: the stamp travels atomically with the data, so no flag round trip.
__device__ __forceinline__ ull ld8a(const ull* p){
  return __hip_atomic_load((ull*)p, __ATOMIC_RELAXED, __HIP_MEMORY_SCOPE_AGENT);
}
__device__ __forceinline__ void st8a(ull* p, ull v){
  __hip_atomic_store(p, v, __ATOMIC_RELAXED, __HIP_MEMORY_SCOPE_AGENT);
}

namespace {
constexpr int NB = 32, TT = 512, DD = 768, HH = 512;
// byte offsets into ws
constexpr size_t EPB  = 0;                               // ep bf16 [B][H][T]; first 2MB doubles as stamped spart after preload
constexpr size_t XBB  = EPB  + (size_t)NB*HH*TT*2;       // x bf16 [B][T][D]
constexpr size_t HSB  = XBB  + (size_t)NB*TT*DD*2;       // hs bf16 [2][T][B][H]
constexpr size_t WPKB = HSB  + (size_t)2*TT*NB*HH*2;     // Wpack bf16 [2][128][64][64][8]
constexpr size_t WDPB = WPKB + (size_t)2*128*64*64*8*2;  // Wdec pack bf16 [32][16][64][8]
constexpr size_t CTXB = WDPB + (size_t)32*16*64*8*2;     // ctxf bf16 [2][32][768]
constexpr size_t EVGB = CTXB + (size_t)2*NB*DD*4;        // evt_u ull [32][2][512] stamped (256KB)
constexpr size_t CSTB = EVGB + (size_t)NB*2*512*8;       // c f32 [2][B][H]
constexpr size_t GSYB = CSTB + (size_t)2*NB*HH*4;        // flags 16KB
constexpr size_t WS_BYTES = GSYB + 49152;

// dynamic LDS layout (bytes)
constexpr int EPL  = 0;           // ushort[64 h][512 t]   ep slice, pinned
constexpr int WPL  = 65536;       // ushort[64][512]       wpk slice, pinned
constexpr int REDL = 131072;      // f32[8][32][16]        MFMA partials
constexpr int HEVL = 147456;      // f32[8][132]           EVT padded
constexpr int HBL  = 151680;      // ushort[8][136]        h staging padded
constexpr int DPL  = 153856;      // f32[512]              Zp partials / zinv
constexpr int DECL = 155904;      // f32[2][64]            dec slice
constexpr int VVL  = 156416;      // f32[64]               v slice, pinned
constexpr int CSCL = 156672;      // f32[8][97]            ctx partials
constexpr int GFNL = 159776;      // f32[32][17]           gate finals
constexpr int LDS_BYTES = GFNL + 2176;   // 161952 <= 163840
}

// ---- global barrier
__device__ __forceinline__ void bar_arrive(uint* flags, uint token, int bid){
  __syncthreads();   // compiler emits s_waitcnt vmcnt(0) before s_barrier => release
  if (threadIdx.x == 0)
    __hip_atomic_store(&flags[bid*16], token, __ATOMIC_RELAXED, __HIP_MEMORY_SCOPE_AGENT);
}
__device__ __forceinline__ void bar_wait(uint* flags, uint token){
  if (threadIdx.x < 256) {
    while (__hip_atomic_load(&flags[threadIdx.x*16], __ATOMIC_RELAXED, __HIP_MEMORY_SCOPE_AGENT) < token)
      __builtin_amdgcn_s_sleep(1);
  }
  __syncthreads();
  asm volatile("" ::: "memory");
}

// ---------------- x -> bf16
__global__ void k_xcast(const float* __restrict__ x, ushort* __restrict__ xb)
{
  size_t i = ((size_t)blockIdx.x*256 + threadIdx.x)*8;
  float4 v0 = *(const float4*)(x + i);
  float4 v1 = *(const float4*)(x + i + 4);
  short8v o;
  o[0]=(short)f2bf(v0.x); o[1]=(short)f2bf(v0.y); o[2]=(short)f2bf(v0.z); o[3]=(short)f2bf(v0.w);
  o[4]=(short)f2bf(v1.x); o[5]=(short)f2bf(v1.y); o[6]=(short)f2bf(v1.z); o[7]=(short)f2bf(v1.w);
  *(short8v*)(xb + i) = o;
}

// ---------------- enc projection
__global__ void k_encproj(const float* __restrict__ x, const float* __restrict__ Wenc,
                          const float* __restrict__ benc, ushort* __restrict__ epT)
{
  int b = blockIdx.z, h0 = blockIdx.y*64, t0 = blockIdx.x*64;
  __shared__ float As[64][33];
  __shared__ float Bs[64][33];
  int tid = threadIdx.x;
  int n = tid & 63, mg = tid >> 6;
  float acc[16];
  #pragma unroll
  for (int j = 0; j < 16; j++) acc[j] = 0.f;
  int lr = tid >> 2, lk = (tid & 3) * 8;
  for (int k0 = 0; k0 < 768; k0 += 32) {
    const float* ap = Wenc + (size_t)(h0 + lr)*768 + k0 + lk;
    #pragma unroll
    for (int i = 0; i < 8; i++) As[lr][lk + i] = ap[i];
    const float* bp = x + ((size_t)b*512 + t0 + lr)*768 + k0 + lk;
    #pragma unroll
    for (int i = 0; i < 8; i++) Bs[lr][lk + i] = bp[i];
    __syncthreads();
    #pragma unroll
    for (int kk = 0; kk < 32; kk++) {
      float bv = Bs[n][kk];
      #pragma unroll
      for (int j = 0; j < 16; j++) acc[j] += As[mg*16 + j][kk] * bv;
    }
    __syncthreads();
  }
  #pragma unroll
  for (int j = 0; j < 16; j++) {
    int h = h0 + mg*16 + j;
    epT[((size_t)b*512 + h)*512 + t0 + n] = f2bf(acc[j] + benc[h]);
  }
}

// ---------------- pre-pack gate weights into MFMA fragment order
__global__ void k_wpack(const float* __restrict__ Wfih, const float* __restrict__ Wfhh,
                        const float* __restrict__ Wbih, const float* __restrict__ Wbhh,
                        ushort* __restrict__ wpk)
{
  size_t f = (size_t)blockIdx.x*256 + threadIdx.x;   // 1,048,576 total
  int lane = (int)(f & 63), kstep = (int)((f>>6)&63), jblk = (int)((f>>12)&127), dir = (int)(f>>19);
  const float* Whh = dir ? Wbhh : Wfhh;
  const float* Wih = dir ? Wbih : Wfih;
  int c = lane & 15, gate = c >> 2, jj = c & 3;
  int row = gate*512 + jblk*4 + jj;
  int kbase = kstep*32 + (lane>>4)*8;
  short8v o;
  #pragma unroll
  for (int i = 0; i < 8; i++) {
    int k = kbase + i;
    float w = (k < 512) ? Whh[(size_t)row*512 + k] : Wih[(size_t)row*1536 + (k - 512)];
    o[i] = (short)f2bf(w);
  }
  *(short8v*)(wpk + f*8) = o;
}

// ---------------- pre-pack Wdec
__global__ void k_wdpack(const float* __restrict__ Wdec, ushort* __restrict__ wdp)
{
  int f = blockIdx.x*256 + threadIdx.x;   // 32768 total
  int lane = f & 63, kstep = (f >> 6) & 15, nb = f >> 10;
  int n = nb*16 + (lane & 15);
  int kbase = kstep*32 + (lane >> 4)*8;
  short8v o;
  #pragma unroll
  for (int i = 0; i < 8; i++) o[i] = (short)f2bf(Wdec[(size_t)n*512 + kbase + i]);
  *(short8v*)(wdp + (size_t)f*8) = o;
}

// ---- gates h-part (waves 0-1) MFMA -> RED rows 0-1. Plain cached loads.
__device__ __forceinline__ void gates_h(int s, int wid, int lane, int l15, int lk8, int dirG,
    const ushort* __restrict__ hsb, const ushort* wpk_l, float* RED)
{
  if (wid >= 2) return;
  int b0 = l15, b1 = 16 + l15;
  f32x4 acc0 = {0,0,0,0}, acc1 = {0,0,0,0};
  if (s > 0) {
    int t_prev = dirG ? (512 - s) : (s - 1);
    const ushort* h0 = hsb + (((size_t)dirG*512 + t_prev)*32 + b0)*512;
    const ushort* h1 = hsb + (((size_t)dirG*512 + t_prev)*32 + b1)*512;
    #pragma unroll
    for (int kk = 0; kk < 8; kk++) {
      int kstep = wid*8 + kk;
      int ko = kstep*32 + lk8;
      short8v a0v = *(const short8v*)(h0 + ko);
      short8v a1v = *(const short8v*)(h1 + ko);
      short8v bv  = *(const short8v*)(wpk_l + (size_t)kstep*512 + lane*8);
      acc0 = __builtin_amdgcn_mfma_f32_16x16x32_bf16(a0v, bv, acc0, 0, 0, 0);
      acc1 = __builtin_amdgcn_mfma_f32_16x16x32_bf16(a1v, bv, acc1, 0, 0, 0);
    }
  }
  int rr = (lane >> 4) * 4;
  #pragma unroll
  for (int r = 0; r < 4; r++) RED[((size_t)wid*32 + rr + r)*16 + l15] = acc0[r];
  #pragma unroll
  for (int r = 0; r < 4; r++) RED[((size_t)wid*32 + 16 + rr + r)*16 + l15] = acc1[r];
}

// ---- gates x-part (waves 5-7) MFMA -> RED rows 5-7. Plain cached loads.
__device__ __forceinline__ void gates_x(int s, int wid, int lane, int l15, int lk8, int dirG,
    const ushort* __restrict__ xb, const ushort* wpk_l, float* RED)
{
  if (wid < 5) return;
  int b0 = l15, b1 = 16 + l15;
  f32x4 acc0 = {0,0,0,0}, acc1 = {0,0,0,0};
  int t_in = dirG ? (511 - s) : s;
  const ushort* x0 = xb + ((size_t)b0*512 + t_in)*768;
  const ushort* x1 = xb + ((size_t)b1*512 + t_in)*768;
  #pragma unroll
  for (int kk = 0; kk < 8; kk++) {
    int kstep = wid*8 + kk;
    int ko = kstep*32 - 1280 + lk8;
    short8v a0v = *(const short8v*)(x0 + ko);
    short8v a1v = *(const short8v*)(x1 + ko);
    short8v bv  = *(const short8v*)(wpk_l + (size_t)kstep*512 + lane*8);
    acc0 = __builtin_amdgcn_mfma_f32_16x16x32_bf16(a0v, bv, acc0, 0, 0, 0);
    acc1 = __builtin_amdgcn_mfma_f32_16x16x32_bf16(a1v, bv, acc1, 0, 0, 0);
  }
  int rr = (lane >> 4) * 4;
  #pragma unroll
  for (int r = 0; r < 4; r++) RED[((size_t)wid*32 + rr + r)*16 + l15] = acc0[r];
  #pragma unroll
  for (int r = 0; r < 4; r++) RED[((size_t)wid*32 + 16 + rr + r)*16 + l15] = acc1[r];
}

// ---------------- persistent loop: stamped single-hop A3 exchange, 2 global barriers/step
__global__ __launch_bounds__(512, 1) void k_loop(
    ushort* __restrict__ hsb, const ushort* __restrict__ xb, const ushort* __restrict__ ep,
    const ushort* __restrict__ wpk, const ushort* __restrict__ wdp,
    ull* __restrict__ spart_u, ushort* __restrict__ ctxf, ull* __restrict__ evt_u,
    float* __restrict__ cst, const float* __restrict__ bdec, const float* __restrict__ vg,
    const float* __restrict__ bfv, const float* __restrict__ bbv,
    uint* __restrict__ flags)
{
  extern __shared__ __align__(16) char dsm[];
  ushort* ep_l  = (ushort*)(dsm + EPL);    // [64 h][512 t]
  ushort* wpk_l = (ushort*)(dsm + WPL);    // [64 kstep][512]
  float*  RED   = (float*)(dsm + REDL);    // [8][32][16]
  float*  HEV   = (float*)(dsm + HEVL);    // [8][132]
  ushort* HB    = (ushort*)(dsm + HBL);    // [8][136]
  float*  DP    = (float*)(dsm + DPL);     // [512]
  float*  DEC   = (float*)(dsm + DECL);    // [2][64]
  float*  VV    = (float*)(dsm + VVL);     // [64]
  float*  CSC   = (float*)(dsm + CSCL);    // [8][97]
  float*  GFIN  = (float*)(dsm + GFNL);    // [32][17]

  const int bid = blockIdx.x;
  const int tid = threadIdx.x;
  const int wid = tid >> 6, lane = tid & 63;
  const int l15 = lane & 15, lk8 = (lane >> 4) * 8;
  const int bS = bid >> 3, hc = bid & 7;               // attention role
  const int dirG = bid >> 7, jblkG = bid & 127;        // gates role
  uint bar_t = 0;

  // ---- one-time preload of pinned LDS
  {
    const short8v* esrc = (const short8v*)(ep + ((size_t)bS*512 + hc*64)*512);
    short8v* edst = (short8v*)ep_l;
    for (int i = tid; i < 4096; i += 512) edst[i] = esrc[i];
    const short8v* wsrc = (const short8v*)(wpk + (((size_t)dirG*128 + jblkG)*64)*512);
    short8v* wdst = (short8v*)wpk_l;
    for (int i = tid; i < 4096; i += 512) wdst[i] = wsrc[i];
    if (tid < 64) VV[tid] = vg[hc*64 + tid];
  }
  ++bar_t; bar_arrive(flags, bar_t, bid);
  gates_x(0, wid, lane, l15, lk8, dirG, xb, wpk_l, RED);   // prologue x-part for s=0
  bar_wait(flags, bar_t);

  for (int s = 0; s < TT; ++s) {
    const uint want = 0xA0000000u | (uint)(s + 1);
    // Stale-stamp safety: spart overlays ep, which k_encproj fully rewrites every
    // replay; a garbage stamp would need the high-16 bf16 == 0xA0xx (a ~1e-29
    // denormal) which f2bf of O(0.1..2) data never produces. evt_u is memset
    // per launch.

    // ======== A1: local dec slice (plain h loads)
    if (s == 0) {
      if (tid < 128) { int dir = tid >> 6, n = tid & 63; DEC[dir*64 + n] = bdec[hc*64 + n]; }
    } else {
      if (tid < 128) {
        int dir = tid >> 6, q = tid & 63;
        int tp = dir ? (512 - s) : (s - 1);
        short8v hv = *(const short8v*)(hsb + (((size_t)dir*512 + tp)*32 + bS)*512 + q*8);
        *(short8v*)&HB[(dir*4 + (q >> 4))*136 + (q & 15)*8] = hv;
      }
      __syncthreads();
      {
        int dir = tid >> 8, n = (tid >> 2) & 63, kq = tid & 3;
        int ng = hc*64 + n, nb = ng >> 4, c = ng & 15;
        const ushort* hrow = HB + (dir*4 + kq)*136;
        float a = 0.f;
        #pragma unroll
        for (int ch = 0; ch < 16; ch++) {
          int kstep = kq*4 + (ch >> 2), lhi = ch & 3;
          short8v w8 = *(const short8v*)(wdp + (((size_t)nb*16 + kstep)*64 + lhi*16 + c)*8);
          #pragma unroll
          for (int j = 0; j < 8; j++) a += bf2f((ushort)w8[j]) * bf2f(hrow[ch*8 + j]);
        }
        DP[tid] = a;
      }
      __syncthreads();
      if (tid < 128) {
        int dir = tid >> 6, n = tid & 63;
        const float* dp = DP + dir*256 + n*4;
        DEC[dir*64 + n] = dp[0] + dp[1] + dp[2] + dp[3] + bdec[hc*64 + n];
      }
    }
    __syncthreads();

    // ======== A2: score partials for this 64-h slice, all 512 t
    float s0 = 0.f, s1 = 0.f;
    {
      int t = tid;
      #pragma unroll 8
      for (int h = 0; h < 64; h++) {
        float e = bf2f(ep_l[h*512 + t]);
        float vv = VV[h];
        s0 += tanh_f(e + DEC[h]) * vv;
        s1 += tanh_f(e + DEC[64 + h]) * vv;
      }
    }

    // ======== A3: stamped single-hop exchange -> designated softmax -> stamped EVT
    if (hc != 0) {
      // mates: fire stamped partials immediately (per-thread, no block sync needed)
      ull hi = ((ull)want) << 32;
      st8a(spart_u + (((size_t)(bS*8 + hc))*2 + 0)*512 + tid, hi | (ull)__float_as_uint(s0));
      st8a(spart_u + (((size_t)(bS*8 + hc))*2 + 1)*512 + tid, hi | (ull)__float_as_uint(s1));
      gates_h(s, wid, lane, l15, lk8, dirG, hsb, wpk_l, RED);   // shadow designated's work
      // poll stamped EVT directly (one hop)
      float e0 = 0.f, e1 = 0.f;
      {
        uint pend = 3u;
        while (pend) {
          if (pend & 1u) {
            ull u = ld8a(evt_u + ((size_t)bS*2 + 0)*512 + tid);
            if ((uint)(u >> 32) == want) { e0 = __uint_as_float((uint)u); pend &= ~1u; }
          }
          if (pend & 2u) {
            ull u = ld8a(evt_u + ((size_t)bS*2 + 1)*512 + tid);
            if ((uint)(u >> 32) == want) { e1 = __uint_as_float((uint)u); pend &= ~2u; }
          }
          if (pend) __builtin_amdgcn_s_sleep(1);
        }
      }
      HEV[(tid >> 7)*132 + (tid & 127)] = e0;
      HEV[(4 + (tid >> 7))*132 + (tid & 127)] = e1;
      __syncthreads();
    } else {
      // designated: poll 14 stamped slots (fully unrolled, register-resident)
      float v0,v1,v2,v3,v4,v5,v6,v7,v8,v9,v10,v11,v12,v13;
      v0=v1=v2=v3=v4=v5=v6=v7=v8=v9=v10=v11=v12=v13=0.f;
      {
        uint pend = 0x3FFFu;
        while (pend) {
          #pragma unroll
          for (int k = 0; k < 14; k++) {
            if (pend & (1u << k)) {
              int j = (k >> 1) + 1, dir = k & 1;
              ull u = ld8a(spart_u + (((size_t)(bS*8 + j))*2 + dir)*512 + tid);
              if ((uint)(u >> 32) == want) {
                float f = __uint_as_float((uint)u);
                switch (k) {
                  case 0: v0=f; break; case 1: v1=f; break; case 2: v2=f; break;
                  case 3: v3=f; break; case 4: v4=f; break; case 5: v5=f; break;
                  case 6: v6=f; break; case 7: v7=f; break; case 8: v8=f; break;
                  case 9: v9=f; break; case 10: v10=f; break; case 11: v11=f; break;
                  case 12: v12=f; break; default: v13=f; break;
                }
                pend &= ~(1u << k);
              }
            }
          }
          if (pend) __builtin_amdgcn_s_sleep(1);
        }
      }
      float s0r = s0 + v0 + v2 + v4 + v6 + v8 + v10 + v12;
      float s1r = s1 + v1 + v3 + v5 + v7 + v9 + v11 + v13;
      s0r = fminf(s0r, 100.f); s1r = fminf(s1r, 100.f);
      float e0 = fexp2((s0r - 32.f)*L2E);
      float e1 = fexp2((s1r - 32.f)*L2E);
      float z0 = e0, z1 = e1;
      #pragma unroll
      for (int off = 32; off; off >>= 1) { z0 += __shfl_xor(z0, off); z1 += __shfl_xor(z1, off); }
      if (lane == 0) { DP[wid] = z0; DP[8 + wid] = z1; }
      __syncthreads();
      if (tid < 2) {
        float z = 0.f;
        #pragma unroll
        for (int w = 0; w < 8; w++) z += DP[tid*8 + w];
        DP[128 + tid] = frcp(z);
      }
      __syncthreads();
      e0 *= DP[128]; e1 *= DP[129];                      // pre-normalized EVT
      ull hi = ((ull)want) << 32;
      st8a(evt_u + ((size_t)bS*2 + 0)*512 + tid, hi | (ull)__float_as_uint(e0));
      st8a(evt_u + ((size_t)bS*2 + 1)*512 + tid, hi | (ull)__float_as_uint(e1));
      HEV[(tid >> 7)*132 + (tid & 127)] = e0;
      HEV[(4 + (tid >> 7))*132 + (tid & 127)] = e1;
      __syncthreads();
    }

    // ======== A4: ctx for this block's 96-dd slice -> bf16 ctxf
    if (tid < 384) {
      int dl = tid % 96, tq = tid / 96;
      const ushort* xp = xb + (((size_t)bS*512 + tq*128)*768) + hc*96 + dl;
      const float* ev0 = HEV + tq*132;
      const float* ev1 = HEV + (4 + tq)*132;
      float a0 = 0.f, a1 = 0.f;
      #pragma unroll 8
      for (int t2 = 0; t2 < 128; t2++) {
        float xv = bf2f(xp[(size_t)t2*768]);
        a0 += ev0[t2]*xv;
        a1 += ev1[t2]*xv;
      }
      CSC[(tq*2 + 0)*97 + dl] = a0;
      CSC[(tq*2 + 1)*97 + dl] = a1;
    }
    __syncthreads();
    if (tid < 192) {
      int dl = tid % 96, dir = tid / 96;
      float cv = CSC[(0*2 + dir)*97 + dl] + CSC[(1*2 + dir)*97 + dl]
               + CSC[(2*2 + dir)*97 + dl] + CSC[(3*2 + dir)*97 + dl];
      st2h(ctxf + ((size_t)dir*32 + bS)*768 + hc*96 + dl, f2bf(cv));
    }

    // ---- global barrier (ctx ready); designated shadows gates_h here
    ++bar_t; bar_arrive(flags, bar_t, bid);
    if (hc == 0) gates_h(s, wid, lane, l15, lk8, dirG, hsb, wpk_l, RED);
    bar_wait(flags, bar_t);

    // ======== G: ctx-part MFMA (waves 2-4, agent reads) + reduce + LSTM + h store
    {
      if (wid >= 2 && wid <= 4) {
        int b0 = l15, b1 = 16 + l15;
        f32x4 acc0 = {0,0,0,0}, acc1 = {0,0,0,0};
        const ushort* c0 = ctxf + ((size_t)dirG*32 + b0)*768;
        const ushort* c1 = ctxf + ((size_t)dirG*32 + b1)*768;
        #pragma unroll
        for (int kk = 0; kk < 8; kk++) {
          int kstep = wid*8 + kk;
          int ko = kstep*32 - 512 + lk8;
          short8v a0v = ld16h(c0 + ko);
          short8v a1v = ld16h(c1 + ko);
          short8v bv  = *(const short8v*)(wpk_l + (size_t)kstep*512 + lane*8);
          acc0 = __builtin_amdgcn_mfma_f32_16x16x32_bf16(a0v, bv, acc0, 0, 0, 0);
          acc1 = __builtin_amdgcn_mfma_f32_16x16x32_bf16(a1v, bv, acc1, 0, 0, 0);
        }
        int rr = (lane >> 4) * 4;
        #pragma unroll
        for (int r = 0; r < 4; r++) RED[((size_t)wid*32 + rr + r)*16 + l15] = acc0[r];
        #pragma unroll
        for (int r = 0; r < 4; r++) RED[((size_t)wid*32 + 16 + rr + r)*16 + l15] = acc1[r];
      }
      __syncthreads();
      {
        int bb = tid >> 4, c = tid & 15;
        float g = 0.f;
        #pragma unroll
        for (int w = 0; w < 8; w++) g += RED[((size_t)w*32 + bb)*16 + c];
        GFIN[bb*17 + c] = g;
      }
      __syncthreads();
      if (tid < 32) {
        int b = tid;
        int j0 = jblkG*4;
        const float* bias = dirG ? bbv : bfv;
        size_t ci0 = ((size_t)dirG*32 + b)*512 + j0;
        float4 co = *(const float4*)&cst[ci0];
        float cold[4] = {co.x, co.y, co.z, co.w};
        float4 cn4;
        ull hp = 0;
        #pragma unroll
        for (int jj = 0; jj < 4; jj++) {
          int j = j0 + jj;
          float gi  = GFIN[b*17 + jj]       + bias[j];
          float gf  = GFIN[b*17 + 4 + jj]   + bias[512 + j];
          float gg  = GFIN[b*17 + 8 + jj]   + bias[1024 + j];
          float go_ = GFIN[b*17 + 12 + jj]  + bias[1536 + j];
          float cn = sigm_f(gf)*cold[jj] + sigm_f(gi)*tanh_f(gg);
          float h  = sigm_f(go_)*tanh_f(cn);
          ((float*)&cn4)[jj] = cn;
          hp |= ((ull)f2bf(h)) << (16*jj);
        }
        *(float4*)&cst[ci0] = cn4;
        int tw = dirG ? (511 - s) : s;
        st8u(hsb + (((size_t)dirG*512 + tw)*32 + b)*512 + j0, hp);
      }
    }
    ++bar_t; bar_arrive(flags, bar_t, bid);
    if (s + 1 < TT)
      gates_x(s + 1, wid, lane, l15, lk8, dirG, xb, wpk_l, RED);  // bar3 shadow (waves 5-7)
    bar_wait(flags, bar_t);
  }
}

// ---------------- head
__global__ void k_head(const ushort* __restrict__ hsb, const float* __restrict__ Wh,
                       const float* __restrict__ bh, float* __restrict__ out)
{
  int wid = threadIdx.x >> 6, lane = threadIdx.x & 63;
  int r = blockIdx.x*4 + wid;
  int b = r >> 9, t = r & 511;
  float acc[7];
  #pragma unroll
  for (int c = 0; c < 7; c++) acc[c] = 0.f;
  const ushort* hf = hsb + (((size_t)t)*32 + b)*512;
  const ushort* hb = hsb + (((size_t)512 + t)*32 + b)*512;
  for (int k0 = 0; k0 < 512; k0 += 64) {
    int k = k0 + lane;
    float a = bf2f(hf[k]), bvv = bf2f(hb[k]);
    #pragma unroll
    for (int c = 0; c < 7; c++)
      acc[c] += a*Wh[c*1024 + k] + bvv*Wh[c*1024 + 512 + k];
  }
  #pragma unroll
  for (int c = 0; c < 7; c++) {
    float sres = acc[c];
    #pragma unroll
    for (int off = 32; off; off >>= 1) sres += __shfl_xor(sres, off);
    if (lane == c) out[((size_t)b*512 + t)*7 + c] = sres + bh[c];
  }
}

extern "C" void kernel_launch(void* const* d_in, const int* in_sizes, int n_in,
                              void* d_out, int out_size, void* d_ws, size_t ws_size,
                              hipStream_t stream) {
  (void)in_sizes; (void)n_in; (void)out_size;
  const float* x    = (const float*)d_in[0];
  const float* Wfih = (const float*)d_in[1];
  const float* Wfhh = (const float*)d_in[2];
  const float* bfv  = (const float*)d_in[3];
  const float* Wbih = (const float*)d_in[4];
  const float* Wbhh = (const float*)d_in[5];
  const float* bbv  = (const float*)d_in[6];
  const float* Wenc = (const float*)d_in[7];
  const float* benc = (const float*)d_in[8];
  const float* Wdec = (const float*)d_in[9];
  const float* bdec = (const float*)d_in[10];
  const float* v    = (const float*)d_in[11];
  const float* Whead= (const float*)d_in[12];
  const float* bhead= (const float*)d_in[13];
  float* out = (float*)d_out;
  char* ws = (char*)d_ws;

  if (ws_size < WS_BYTES) return;

  ushort* ep   = (ushort*)(ws + EPB);
  ull*    spart= (ull*)(ws + EPB);         // overlays ep; safe after barrier0 (ep rewritten each replay)
  ushort* xb   = (ushort*)(ws + XBB);
  ushort* hsb  = (ushort*)(ws + HSB);
  ushort* wpk  = (ushort*)(ws + WPKB);
  ushort* wdp  = (ushort*)(ws + WDPB);
  ushort* ctxf = (ushort*)(ws + CTXB);
  ull*    evtu = (ull*)(ws + EVGB);
  float*  cst  = (float*)(ws + CSTB);
  uint*   flags= (uint*)(ws + GSYB);

  hipFuncSetAttribute(reinterpret_cast<const void*>(k_loop),
                      hipFuncAttributeMaxDynamicSharedMemorySize, LDS_BYTES);

  hipMemsetAsync(ws + CSTB, 0, (size_t)2*NB*HH*4, stream);
  hipMemsetAsync(ws + GSYB, 0, 49152, stream);
  hipMemsetAsync(ws + EVGB, 0, (size_t)NB*2*512*8, stream);   // kill stale EVT stamps across replays

  hipLaunchKernelGGL(k_xcast, dim3(6144), dim3(256), 0, stream, x, xb);
  hipLaunchKernelGGL(k_encproj, dim3(8,8,32), dim3(256), 0, stream, x, Wenc, benc, ep);
  hipLaunchKernelGGL(k_wpack, dim3(4096), dim3(256), 0, stream, Wfih, Wfhh, Wbih, Wbhh, wpk);
  hipLaunchKernelGGL(k_wdpack, dim3(128), dim3(256), 0, stream, Wdec, wdp);

  void* args[] = {
    (void*)&hsb, (void*)&xb, (void*)&ep, (void*)&wpk, (void*)&wdp,
    (void*)&spart, (void*)&ctxf, (void*)&evtu, (void*)&cst,
    (void*)&bdec, (void*)&v, (void*)&bfv, (void*)&bbv,
    (void*)&flags
  };
  hipLaunchCooperativeKernel(reinterpret_cast<void*>(k_loop), dim3(256), dim3(512),
                             args, LDS_BYTES, stream);

  hipLaunchKernelGGL(k_head, dim3(4096), dim3(256), 0, stream, hsb, Whead, bhead, out);
}

// Round 15
// 13548.019 us; speedup vs baseline: 1.2276x; 1.2276x over previous
//
#include <hip/hip_runtime.h>
#include <cstdint>
#include <cstddef>

#define L2E 1.4426950408889634f

typedef __attribute__((ext_vector_type(8))) short short8v;
typedef __attribute__((ext_vector_type(4))) float f32x4;
typedef unsigned long long ull;

__device__ __forceinline__ float fexp2(float x){ return __builtin_amdgcn_exp2f(x); }
__device__ __forceinline__ float frcp(float x){ return __builtin_amdgcn_rcpf(x); }
__device__ __forceinline__ float tanh_f(float x){
  return 1.f - 2.f*frcp(1.f + fexp2(2.f*L2E*x));
}
__device__ __forceinline__ float sigm_f(float x){
  return frcp(1.f + fexp2(-L2E*x));
}
__device__ __forceinline__ float bf2f(ushort u){ return __uint_as_float(((uint32_t)u)<<16); }
__device__ __forceinline__ ushort f2bf(float f){
  uint32_t x = __float_as_uint(f);
  uint32_t r = (x + 0x7FFFu + ((x>>16)&1u)) >> 16;
  return (ushort)r;
}

// ---- coherent (agent-scope) access helpers: only for within-run rewritten data
__device__ __forceinline__ float ld4f(const float* p){
  return __hip_atomic_load((float*)p, __ATOMIC_RELAXED, __HIP_MEMORY_SCOPE_AGENT);
}
__device__ __forceinline__ void st4f(float* p, float v){
  __hip_atomic_store(p, v, __ATOMIC_RELAXED, __HIP_MEMORY_SCOPE_AGENT);
}
__device__ __forceinline__ void st2h(ushort* p, ushort v){
  __hip_atomic_store(p, v, __ATOMIC_RELAXED, __HIP_MEMORY_SCOPE_AGENT);
}
__device__ __forceinline__ short8v ld16h(const ushort* p){
  union { ull u[2]; short8v s; } c;
  c.u[0] = __hip_atomic_load((ull*)p,     __ATOMIC_RELAXED, __HIP_MEMORY_SCOPE_AGENT);
  c.u[1] = __hip_atomic_load((ull*)(p+4), __ATOMIC_RELAXED, __HIP_MEMORY_SCOPE_AGENT);
  return c.s;
}
__device__ __forceinline__ void st8u(ushort* p, ull v){
  __hip_atomic_store((ull*)p, v, __ATOMIC_RELAXED, __HIP_MEMORY_SCOPE_AGENT);
}

namespace {
constexpr int NB = 32, TT = 512, DD = 768, HH = 512;
// byte offsets into ws
constexpr size_t EPB  = 0;                               // ep bf16 [B][H][T]; first 2MB doubles as spart after preload
constexpr size_t XBB  = EPB  + (size_t)NB*HH*TT*2;       // x bf16 [B][T][D]
constexpr size_t HSB  = XBB  + (size_t)NB*TT*DD*2;       // hs bf16 [2][T][B][H]
constexpr size_t WPKB = HSB  + (size_t)2*TT*NB*HH*2;     // Wpack bf16 [2][128][64][64][8]
constexpr size_t WDPB = WPKB + (size_t)2*128*64*64*8*2;  // Wdec pack bf16 [32][16][64][8]
constexpr size_t CTXB = WDPB + (size_t)32*16*64*8*2;     // ctxf bf16 [2][32][768]
constexpr size_t EVGB = CTXB + (size_t)2*NB*DD*4;        // evt_g f32 [32][2][512]
constexpr size_t CSTB = EVGB + (size_t)NB*2*512*4;       // c f32 [2][B][H]
constexpr size_t GSYB = CSTB + (size_t)2*NB*HH*4;        // flags 16KB | gfl 16KB | gfl2 16KB
constexpr size_t WS_BYTES = GSYB + 49152;

// dynamic LDS layout (bytes)
constexpr int EPL  = 0;           // ushort[64 h][512 t]   ep slice, pinned
constexpr int WPL  = 65536;       // ushort[64][512]       wpk slice, pinned
constexpr int REDL = 131072;      // f32[8][32][16]        MFMA partials
constexpr int HEVL = 147456;      // f32[8][132]           EVT padded
constexpr int HBL  = 151680;      // ushort[8][136]        h staging padded
constexpr int DPL  = 153856;      // f32[512]              Zp partials / zinv
constexpr int DECL = 155904;      // f32[2][64]            dec slice
constexpr int VVL  = 156416;      // f32[64]               v slice, pinned
constexpr int CSCL = 156672;      // f32[8][97]            ctx partials
constexpr int GFNL = 159776;      // f32[32][17]           gate finals
constexpr int LDS_BYTES = GFNL + 2176;   // 161952 <= 163840
}

// ---- global barrier
__device__ __forceinline__ void bar_arrive(uint* flags, uint token, int bid){
  __syncthreads();   // compiler emits s_waitcnt vmcnt(0) before s_barrier => release
  if (threadIdx.x == 0)
    __hip_atomic_store(&flags[bid*16], token, __ATOMIC_RELAXED, __HIP_MEMORY_SCOPE_AGENT);
}
__device__ __forceinline__ void bar_wait(uint* flags, uint token){
  if (threadIdx.x < 256) {
    while (__hip_atomic_load(&flags[threadIdx.x*16], __ATOMIC_RELAXED, __HIP_MEMORY_SCOPE_AGENT) < token)
      __builtin_amdgcn_s_sleep(1);
  }
  __syncthreads();
  asm volatile("" ::: "memory");
}

// ---------------- x -> bf16
__global__ void k_xcast(const float* __restrict__ x, ushort* __restrict__ xb)
{
  size_t i = ((size_t)blockIdx.x*256 + threadIdx.x)*8;
  float4 v0 = *(const float4*)(x + i);
  float4 v1 = *(const float4*)(x + i + 4);
  short8v o;
  o[0]=(short)f2bf(v0.x); o[1]=(short)f2bf(v0.y); o[2]=(short)f2bf(v0.z); o[3]=(short)f2bf(v0.w);
  o[4]=(short)f2bf(v1.x); o[5]=(short)f2bf(v1.y); o[6]=(short)f2bf(v1.z); o[7]=(short)f2bf(v1.w);
  *(short8v*)(xb + i) = o;
}

// ---------------- enc projection
__global__ void k_encproj(const float* __restrict__ x, const float* __restrict__ Wenc,
                          const float* __restrict__ benc, ushort* __restrict__ epT)
{
  int b = blockIdx.z, h0 = blockIdx.y*64, t0 = blockIdx.x*64;
  __shared__ float As[64][33];
  __shared__ float Bs[64][33];
  int tid = threadIdx.x;
  int n = tid & 63, mg = tid >> 6;
  float acc[16];
  #pragma unroll
  for (int j = 0; j < 16; j++) acc[j] = 0.f;
  int lr = tid >> 2, lk = (tid & 3) * 8;
  for (int k0 = 0; k0 < 768; k0 += 32) {
    const float* ap = Wenc + (size_t)(h0 + lr)*768 + k0 + lk;
    #pragma unroll
    for (int i = 0; i < 8; i++) As[lr][lk + i] = ap[i];
    const float* bp = x + ((size_t)b*512 + t0 + lr)*768 + k0 + lk;
    #pragma unroll
    for (int i = 0; i < 8; i++) Bs[lr][lk + i] = bp[i];
    __syncthreads();
    #pragma unroll
    for (int kk = 0; kk < 32; kk++) {
      float bv = Bs[n][kk];
      #pragma unroll
      for (int j = 0; j < 16; j++) acc[j] += As[mg*16 + j][kk] * bv;
    }
    __syncthreads();
  }
  #pragma unroll
  for (int j = 0; j < 16; j++) {
    int h = h0 + mg*16 + j;
    epT[((size_t)b*512 + h)*512 + t0 + n] = f2bf(acc[j] + benc[h]);
  }
}

// ---------------- pre-pack gate weights into MFMA fragment order
__global__ void k_wpack(const float* __restrict__ Wfih, const float* __restrict__ Wfhh,
                        const float* __restrict__ Wbih, const float* __restrict__ Wbhh,
                        ushort* __restrict__ wpk)
{
  size_t f = (size_t)blockIdx.x*256 + threadIdx.x;   // 1,048,576 total
  int lane = (int)(f & 63), kstep = (int)((f>>6)&63), jblk = (int)((f>>12)&127), dir = (int)(f>>19);
  const float* Whh = dir ? Wbhh : Wfhh;
  const float* Wih = dir ? Wbih : Wfih;
  int c = lane & 15, gate = c >> 2, jj = c & 3;
  int row = gate*512 + jblk*4 + jj;
  int kbase = kstep*32 + (lane>>4)*8;
  short8v o;
  #pragma unroll
  for (int i = 0; i < 8; i++) {
    int k = kbase + i;
    float w = (k < 512) ? Whh[(size_t)row*512 + k] : Wih[(size_t)row*1536 + (k - 512)];
    o[i] = (short)f2bf(w);
  }
  *(short8v*)(wpk + f*8) = o;
}

// ---------------- pre-pack Wdec
__global__ void k_wdpack(const float* __restrict__ Wdec, ushort* __restrict__ wdp)
{
  int f = blockIdx.x*256 + threadIdx.x;   // 32768 total
  int lane = f & 63, kstep = (f >> 6) & 15, nb = f >> 10;
  int n = nb*16 + (lane & 15);
  int kbase = kstep*32 + (lane >> 4)*8;
  short8v o;
  #pragma unroll
  for (int i = 0; i < 8; i++) o[i] = (short)f2bf(Wdec[(size_t)n*512 + kbase + i]);
  *(short8v*)(wdp + (size_t)f*8) = o;
}

// ---- gates h-part (waves 0-1) and x-part (waves 5-7) MFMA -> RED.
// h & x read with PLAIN loads: x is read-only; hsb[t] is written (agent) strictly before
// its only within-run read (next step, post-barrier) and is replay-deterministic -> no stale L2.
__device__ __forceinline__ void gates_hx(int s, int wid, int lane, int l15, int lk8, int dirG,
    const ushort* __restrict__ hsb, const ushort* __restrict__ xb,
    const ushort* wpk_l, float* RED)
{
  if (wid >= 2 && wid <= 4) return;
  int b0 = l15, b1 = 16 + l15;
  f32x4 acc0 = {0,0,0,0}, acc1 = {0,0,0,0};
  if (wid < 2) {                       // ksteps 0..15 : h_prev part
    if (s > 0) {
      int t_prev = dirG ? (512 - s) : (s - 1);
      const ushort* h0 = hsb + (((size_t)dirG*512 + t_prev)*32 + b0)*512;
      const ushort* h1 = hsb + (((size_t)dirG*512 + t_prev)*32 + b1)*512;
      #pragma unroll
      for (int kk = 0; kk < 8; kk++) {
        int kstep = wid*8 + kk;
        int ko = kstep*32 + lk8;
        short8v a0v = *(const short8v*)(h0 + ko);
        short8v a1v = *(const short8v*)(h1 + ko);
        short8v bv  = *(const short8v*)(wpk_l + (size_t)kstep*512 + lane*8);
        acc0 = __builtin_amdgcn_mfma_f32_16x16x32_bf16(a0v, bv, acc0, 0, 0, 0);
        acc1 = __builtin_amdgcn_mfma_f32_16x16x32_bf16(a1v, bv, acc1, 0, 0, 0);
      }
    }
  } else {                             // ksteps 40..63 : x part (plain cached loads)
    int t_in = dirG ? (511 - s) : s;
    const ushort* x0 = xb + ((size_t)b0*512 + t_in)*768;
    const ushort* x1 = xb + ((size_t)b1*512 + t_in)*768;
    #pragma unroll
    for (int kk = 0; kk < 8; kk++) {
      int kstep = wid*8 + kk;
      int ko = kstep*32 - 1280 + lk8;
      short8v a0v = *(const short8v*)(x0 + ko);
      short8v a1v = *(const short8v*)(x1 + ko);
      short8v bv  = *(const short8v*)(wpk_l + (size_t)kstep*512 + lane*8);
      acc0 = __builtin_amdgcn_mfma_f32_16x16x32_bf16(a0v, bv, acc0, 0, 0, 0);
      acc1 = __builtin_amdgcn_mfma_f32_16x16x32_bf16(a1v, bv, acc1, 0, 0, 0);
    }
  }
  int rr = (lane >> 4) * 4;
  #pragma unroll
  for (int r = 0; r < 4; r++) RED[((size_t)wid*32 + rr + r)*16 + l15] = acc0[r];
  #pragma unroll
  for (int r = 0; r < 4; r++) RED[((size_t)wid*32 + 16 + rr + r)*16 + l15] = acc1[r];
}

// ---------------- persistent loop (r10 configuration — measured best of family)
__global__ __launch_bounds__(512, 1) void k_loop(
    ushort* __restrict__ hsb, const ushort* __restrict__ xb, const ushort* __restrict__ ep,
    const ushort* __restrict__ wpk, const ushort* __restrict__ wdp,
    float* __restrict__ spart, ushort* __restrict__ ctxf, float* __restrict__ evt_g,
    float* __restrict__ cst, const float* __restrict__ bdec, const float* __restrict__ vg,
    const float* __restrict__ bfv, const float* __restrict__ bbv,
    uint* __restrict__ flags, uint* __restrict__ gfl, uint* __restrict__ gfl2)
{
  extern __shared__ __align__(16) char dsm[];
  ushort* ep_l  = (ushort*)(dsm + EPL);    // [64 h][512 t]
  ushort* wpk_l = (ushort*)(dsm + WPL);    // [64 kstep][512]
  float*  RED   = (float*)(dsm + REDL);    // [8][32][16]
  float*  HEV   = (float*)(dsm + HEVL);    // [8][132]
  ushort* HB    = (ushort*)(dsm + HBL);    // [8][136]
  float*  DP    = (float*)(dsm + DPL);     // [512]
  float*  DEC   = (float*)(dsm + DECL);    // [2][64]
  float*  VV    = (float*)(dsm + VVL);     // [64]
  float*  CSC   = (float*)(dsm + CSCL);    // [8][97]
  float*  GFIN  = (float*)(dsm + GFNL);    // [32][17]

  const int bid = blockIdx.x;
  const int tid = threadIdx.x;
  const int wid = tid >> 6, lane = tid & 63;
  const int l15 = lane & 15, lk8 = (lane >> 4) * 8;
  const int bS = bid >> 3, hc = bid & 7;               // attention role
  const int dirG = bid >> 7, jblkG = bid & 127;        // gates role
  uint bar_t = 0;

  // ---- one-time preload of pinned LDS
  {
    const short8v* esrc = (const short8v*)(ep + ((size_t)bS*512 + hc*64)*512);
    short8v* edst = (short8v*)ep_l;
    for (int i = tid; i < 4096; i += 512) edst[i] = esrc[i];
    const short8v* wsrc = (const short8v*)(wpk + (((size_t)dirG*128 + jblkG)*64)*512);
    short8v* wdst = (short8v*)wpk_l;
    for (int i = tid; i < 4096; i += 512) wdst[i] = wsrc[i];
    if (tid < 64) VV[tid] = vg[hc*64 + tid];
  }
  ++bar_t; bar_arrive(flags, bar_t, bid); bar_wait(flags, bar_t);

  for (int s = 0; s < TT; ++s) {
    // ======== A1: local dec slice (plain h loads)
    if (s == 0) {
      if (tid < 128) { int dir = tid >> 6, n = tid & 63; DEC[dir*64 + n] = bdec[hc*64 + n]; }
    } else {
      if (tid < 128) {
        int dir = tid >> 6, q = tid & 63;
        int tp = dir ? (512 - s) : (s - 1);
        short8v hv = *(const short8v*)(hsb + (((size_t)dir*512 + tp)*32 + bS)*512 + q*8);
        *(short8v*)&HB[(dir*4 + (q >> 4))*136 + (q & 15)*8] = hv;
      }
      __syncthreads();
      {
        int dir = tid >> 8, n = (tid >> 2) & 63, kq = tid & 3;
        int ng = hc*64 + n, nb = ng >> 4, c = ng & 15;
        const ushort* hrow = HB + (dir*4 + kq)*136;
        float a = 0.f;
        #pragma unroll
        for (int ch = 0; ch < 16; ch++) {
          int kstep = kq*4 + (ch >> 2), lhi = ch & 3;
          short8v w8 = *(const short8v*)(wdp + (((size_t)nb*16 + kstep)*64 + lhi*16 + c)*8);
          #pragma unroll
          for (int j = 0; j < 8; j++) a += bf2f((ushort)w8[j]) * bf2f(hrow[ch*8 + j]);
        }
        DP[tid] = a;
      }
      __syncthreads();
      if (tid < 128) {
        int dir = tid >> 6, n = tid & 63;
        const float* dp = DP + dir*256 + n*4;
        DEC[dir*64 + n] = dp[0] + dp[1] + dp[2] + dp[3] + bdec[hc*64 + n];
      }
    }
    __syncthreads();

    // ======== A2: score partials for this 64-h slice, all 512 t
    float s0 = 0.f, s1 = 0.f;
    {
      int t = tid;
      #pragma unroll 8
      for (int h = 0; h < 64; h++) {
        float e = bf2f(ep_l[h*512 + t]);
        float vv = VV[h];
        s0 += tanh_f(e + DEC[h]) * vv;
        s1 += tanh_f(e + DEC[64 + h]) * vv;
      }
    }

    // ======== A3: designated softmax (hc==0) + EVT broadcast; mates shadow with gates_hx
    if (hc != 0) {
      float* sp = spart + (((size_t)(bS*8 + hc))*2)*512;
      st4f(sp + tid, s0);
      st4f(sp + 512 + tid, s1);
      __syncthreads();
      if (tid == 0)
        __hip_atomic_store(&gfl[bid*16], (uint)(s + 1), __ATOMIC_RELAXED, __HIP_MEMORY_SCOPE_AGENT);
      gates_hx(s, wid, lane, l15, lk8, dirG, hsb, xb, wpk_l, RED);
      if (tid == 0) {
        while (__hip_atomic_load(&gfl2[bS*16], __ATOMIC_RELAXED, __HIP_MEMORY_SCOPE_AGENT) < (uint)(s + 1))
          __builtin_amdgcn_s_sleep(1);
      }
      __syncthreads();
      {
        float e0 = ld4f(evt_g + (size_t)bS*1024 + tid);
        float e1 = ld4f(evt_g + (size_t)bS*1024 + 512 + tid);
        HEV[(tid >> 7)*132 + (tid & 127)] = e0;
        HEV[(4 + (tid >> 7))*132 + (tid & 127)] = e1;
      }
      __syncthreads();
    } else {
      if (tid >= 1 && tid < 8) {
        while (__hip_atomic_load(&gfl[(bS*8 + tid)*16], __ATOMIC_RELAXED, __HIP_MEMORY_SCOPE_AGENT) < (uint)(s + 1))
          __builtin_amdgcn_s_sleep(1);
      }
      __syncthreads();
      float s0r = s0, s1r = s1;
      #pragma unroll
      for (int j = 1; j < 8; j++) {
        const float* sp = spart + (((size_t)(bS*8 + j))*2)*512;
        s0r += ld4f(sp + tid);
        s1r += ld4f(sp + 512 + tid);
      }
      s0r = fminf(s0r, 100.f); s1r = fminf(s1r, 100.f);
      float e0 = fexp2((s0r - 32.f)*L2E);
      float e1 = fexp2((s1r - 32.f)*L2E);
      float z0 = e0, z1 = e1;
      #pragma unroll
      for (int off = 32; off; off >>= 1) { z0 += __shfl_xor(z0, off); z1 += __shfl_xor(z1, off); }
      if (lane == 0) { DP[wid] = z0; DP[8 + wid] = z1; }
      __syncthreads();
      if (tid < 2) {
        float z = 0.f;
        #pragma unroll
        for (int w = 0; w < 8; w++) z += DP[tid*8 + w];
        DP[128 + tid] = frcp(z);
      }
      __syncthreads();
      e0 *= DP[128]; e1 *= DP[129];                      // pre-normalized EVT
      HEV[(tid >> 7)*132 + (tid & 127)] = e0;
      HEV[(4 + (tid >> 7))*132 + (tid & 127)] = e1;
      st4f(evt_g + (size_t)bS*1024 + tid, e0);
      st4f(evt_g + (size_t)bS*1024 + 512 + tid, e1);
      __syncthreads();                                   // drains evt stores
      if (tid == 0)
        __hip_atomic_store(&gfl2[bS*16], (uint)(s + 1), __ATOMIC_RELAXED, __HIP_MEMORY_SCOPE_AGENT);
    }

    // ======== A4: ctx for this block's 96-dd slice -> bf16 ctxf
    if (tid < 384) {
      int dl = tid % 96, tq = tid / 96;
      const ushort* xp = xb + (((size_t)bS*512 + tq*128)*768) + hc*96 + dl;
      const float* ev0 = HEV + tq*132;
      const float* ev1 = HEV + (4 + tq)*132;
      float a0 = 0.f, a1 = 0.f;
      #pragma unroll 8
      for (int t2 = 0; t2 < 128; t2++) {
        float xv = bf2f(xp[(size_t)t2*768]);
        a0 += ev0[t2]*xv;
        a1 += ev1[t2]*xv;
      }
      CSC[(tq*2 + 0)*97 + dl] = a0;
      CSC[(tq*2 + 1)*97 + dl] = a1;
    }
    __syncthreads();
    if (tid < 192) {
      int dl = tid % 96, dir = tid / 96;
      float cv = CSC[(0*2 + dir)*97 + dl] + CSC[(1*2 + dir)*97 + dl]
               + CSC[(2*2 + dir)*97 + dl] + CSC[(3*2 + dir)*97 + dl];
      st2h(ctxf + ((size_t)dir*32 + bS)*768 + hc*96 + dl, f2bf(cv));
    }

    // ---- global barrier (ctx ready); designated shadows gates_hx here
    ++bar_t; bar_arrive(flags, bar_t, bid);
    if (hc == 0) gates_hx(s, wid, lane, l15, lk8, dirG, hsb, xb, wpk_l, RED);
    bar_wait(flags, bar_t);

    // ======== G: ctx-part MFMA (waves 2-4, agent reads) + reduce + LSTM + h store
    {
      if (wid >= 2 && wid <= 4) {
        int b0 = l15, b1 = 16 + l15;
        f32x4 acc0 = {0,0,0,0}, acc1 = {0,0,0,0};
        const ushort* c0 = ctxf + ((size_t)dirG*32 + b0)*768;
        const ushort* c1 = ctxf + ((size_t)dirG*32 + b1)*768;
        #pragma unroll
        for (int kk = 0; kk < 8; kk++) {
          int kstep = wid*8 + kk;
          int ko = kstep*32 - 512 + lk8;
          short8v a0v = ld16h(c0 + ko);
          short8v a1v = ld16h(c1 + ko);
          short8v bv  = *(const short8v*)(wpk_l + (size_t)kstep*512 + lane*8);
          acc0 = __builtin_amdgcn_mfma_f32_16x16x32_bf16(a0v, bv, acc0, 0, 0, 0);
          acc1 = __builtin_amdgcn_mfma_f32_16x16x32_bf16(a1v, bv, acc1, 0, 0, 0);
        }
        int rr = (lane >> 4) * 4;
        #pragma unroll
        for (int r = 0; r < 4; r++) RED[((size_t)wid*32 + rr + r)*16 + l15] = acc0[r];
        #pragma unroll
        for (int r = 0; r < 4; r++) RED[((size_t)wid*32 + 16 + rr + r)*16 + l15] = acc1[r];
      }
      __syncthreads();
      {
        int bb = tid >> 4, c = tid & 15;
        float g = 0.f;
        #pragma unroll
        for (int w = 0; w < 8; w++) g += RED[((size_t)w*32 + bb)*16 + c];
        GFIN[bb*17 + c] = g;
      }
      __syncthreads();
      if (tid < 32) {
        int b = tid;
        int j0 = jblkG*4;
        const float* bias = dirG ? bbv : bfv;
        size_t ci0 = ((size_t)dirG*32 + b)*512 + j0;
        float4 co = *(const float4*)&cst[ci0];
        float cold[4] = {co.x, co.y, co.z, co.w};
        float4 cn4;
        ull hp = 0;
        #pragma unroll
        for (int jj = 0; jj < 4; jj++) {
          int j = j0 + jj;
          float gi  = GFIN[b*17 + jj]       + bias[j];
          float gf  = GFIN[b*17 + 4 + jj]   + bias[512 + j];
          float gg  = GFIN[b*17 + 8 + jj]   + bias[1024 + j];
          float go_ = GFIN[b*17 + 12 + jj]  + bias[1536 + j];
          float cn = sigm_f(gf)*cold[jj] + sigm_f(gi)*tanh_f(gg);
          float h  = sigm_f(go_)*tanh_f(cn);
          ((float*)&cn4)[jj] = cn;
          hp |= ((ull)f2bf(h)) << (16*jj);
        }
        *(float4*)&cst[ci0] = cn4;
        int tw = dirG ? (511 - s) : s;
        st8u(hsb + (((size_t)dirG*512 + tw)*32 + b)*512 + j0, hp);
      }
    }
    ++bar_t; bar_arrive(flags, bar_t, bid);
    bar_wait(flags, bar_t);
  }
}

// ---------------- head
__global__ void k_head(const ushort* __restrict__ hsb, const float* __restrict__ Wh,
                       const float* __restrict__ bh, float* __restrict__ out)
{
  int wid = threadIdx.x >> 6, lane = threadIdx.x & 63;
  int r = blockIdx.x*4 + wid;
  int b = r >> 9, t = r & 511;
  float acc[7];
  #pragma unroll
  for (int c = 0; c < 7; c++) acc[c] = 0.f;
  const ushort* hf = hsb + (((size_t)t)*32 + b)*512;
  const ushort* hb = hsb + (((size_t)512 + t)*32 + b)*512;
  for (int k0 = 0; k0 < 512; k0 += 64) {
    int k = k0 + lane;
    float a = bf2f(hf[k]), bvv = bf2f(hb[k]);
    #pragma unroll
    for (int c = 0; c < 7; c++)
      acc[c] += a*Wh[c*1024 + k] + bvv*Wh[c*1024 + 512 + k];
  }
  #pragma unroll
  for (int c = 0; c < 7; c++) {
    float sres = acc[c];
    #pragma unroll
    for (int off = 32; off; off >>= 1) sres += __shfl_xor(sres, off);
    if (lane == c) out[((size_t)b*512 + t)*7 + c] = sres + bh[c];
  }
}

extern "C" void kernel_launch(void* const* d_in, const int* in_sizes, int n_in,
                              void* d_out, int out_size, void* d_ws, size_t ws_size,
                              hipStream_t stream) {
  (void)in_sizes; (void)n_in; (void)out_size;
  const float* x    = (const float*)d_in[0];
  const float* Wfih = (const float*)d_in[1];
  const float* Wfhh = (const float*)d_in[2];
  const float* bfv  = (const float*)d_in[3];
  const float* Wbih = (const float*)d_in[4];
  const float* Wbhh = (const float*)d_in[5];
  const float* bbv  = (const float*)d_in[6];
  const float* Wenc = (const float*)d_in[7];
  const float* benc = (const float*)d_in[8];
  const float* Wdec = (const float*)d_in[9];
  const float* bdec = (const float*)d_in[10];
  const float* v    = (const float*)d_in[11];
  const float* Whead= (const float*)d_in[12];
  const float* bhead= (const float*)d_in[13];
  float* out = (float*)d_out;
  char* ws = (char*)d_ws;

  if (ws_size < WS_BYTES) return;

  ushort* ep   = (ushort*)(ws + EPB);
  float*  spart= (float*)(ws + EPB);       // overlays ep; safe after barrier0
  ushort* xb   = (ushort*)(ws + XBB);
  ushort* hsb  = (ushort*)(ws + HSB);
  ushort* wpk  = (ushort*)(ws + WPKB);
  ushort* wdp  = (ushort*)(ws + WDPB);
  ushort* ctxf = (ushort*)(ws + CTXB);
  float*  evtg = (float*)(ws + EVGB);
  float*  cst  = (float*)(ws + CSTB);
  uint*   flags= (uint*)(ws + GSYB);
  uint*   gfl  = (uint*)(ws + GSYB + 16384);
  uint*   gfl2 = (uint*)(ws + GSYB + 32768);

  hipFuncSetAttribute(reinterpret_cast<const void*>(k_loop),
                      hipFuncAttributeMaxDynamicSharedMemorySize, LDS_BYTES);

  hipMemsetAsync(ws + CSTB, 0, (size_t)2*NB*HH*4, stream);
  hipMemsetAsync(ws + GSYB, 0, 49152, stream);

  hipLaunchKernelGGL(k_xcast, dim3(6144), dim3(256), 0, stream, x, xb);
  hipLaunchKernelGGL(k_encproj, dim3(8,8,32), dim3(256), 0, stream, x, Wenc, benc, ep);
  hipLaunchKernelGGL(k_wpack, dim3(4096), dim3(256), 0, stream, Wfih, Wfhh, Wbih, Wbhh, wpk);
  hipLaunchKernelGGL(k_wdpack, dim3(128), dim3(256), 0, stream, Wdec, wdp);

  void* args[] = {
    (void*)&hsb, (void*)&xb, (void*)&ep, (void*)&wpk, (void*)&wdp,
    (void*)&spart, (void*)&ctxf, (void*)&evtg, (void*)&cst,
    (void*)&bdec, (void*)&v, (void*)&bfv, (void*)&bbv,
    (void*)&flags, (void*)&gfl, (void*)&gfl2
  };
  hipLaunchCooperativeKernel(reinterpret_cast<void*>(k_loop), dim3(256), dim3(512),
                             args, LDS_BYTES, stream);

  hipLaunchKernelGGL(k_head, dim3(4096), dim3(256), 0, stream, hsb, Whead, bhead, out);
}